// Round 11
// baseline (400.528 us; speedup 1.0000x reference)
//
#include <hip/hip_runtime.h>

#define B_ 512
#define S_ 512
#define E_ 128
#define H_ 100
#define T_ 64
#define V_ 100000
#define BS_ (B_*S_)

typedef __attribute__((ext_vector_type(8))) short bf16x8;
typedef __attribute__((ext_vector_type(4))) float f32x4;
union U16x4 { uint4 u; bf16x8 s; };

__device__ __forceinline__ unsigned f2bf1(float x){
    unsigned u = __float_as_uint(x);
    return (u + 0x7FFFu + ((u>>16)&1u)) >> 16;
}
__device__ __forceinline__ float bf2f(unsigned short h){
    return __uint_as_float(((unsigned)h)<<16);
}
__device__ __forceinline__ float rfl_f(float x){
    return __uint_as_float(__builtin_amdgcn_readfirstlane(__float_as_uint(x)));
}
__device__ __forceinline__ unsigned addpack3(unsigned a, unsigned b, unsigned c){
    float lo = __uint_as_float(a<<16) + __uint_as_float(b<<16) + __uint_as_float(c<<16);
    float hi = __uint_as_float(a&0xFFFF0000u) + __uint_as_float(b&0xFFFF0000u)
             + __uint_as_float(c&0xFFFF0000u);
    return f2bf1(lo) | (f2bf1(hi)<<16);
}

// ---------------------------------------------------------------------------
// prep_tbl: fp32 emb table -> bf16 copy (halves mlp gather bytes).
// ---------------------------------------------------------------------------
__global__ __launch_bounds__(256) void prep_tbl(
    const float* __restrict__ tbl, uint2* __restrict__ tblh)
{
    int idx = blockIdx.x*256 + threadIdx.x;
    if (idx < (V_*E_)/4) {
        float4 v = ((const float4*)tbl)[idx];
        uint2 o;
        o.x = f2bf1(v.x) | (f2bf1(v.y)<<16);
        o.y = f2bf1(v.z) | (f2bf1(v.w)<<16);
        tblh[idx] = o;
    }
}

// ---------------------------------------------------------------------------
// prep_w: W1/W2 bf16 MFMA B-fragment images (44 parallel blocks).
// ---------------------------------------------------------------------------
__global__ __launch_bounds__(64) void prep_w(
    const float* __restrict__ W1, const float* __restrict__ W2,
    uint4* __restrict__ W1f, uint4* __restrict__ W2f)
{
    const int idx = blockIdx.x*64 + threadIdx.x;
    if (idx < 7*4*64) {
        int lane = idx & 63, kt = (idx>>6)&3, nt = idx>>8;
        int n = nt*16 + (lane&15);
        int kb = kt*32 + (lane>>4)*8;
        unsigned wv[4];
        #pragma unroll
        for (int p = 0; p < 4; ++p) {
            float v0 = (n < H_) ? W1[(kb+2*p  )*H_ + n] : 0.f;
            float v1 = (n < H_) ? W1[(kb+2*p+1)*H_ + n] : 0.f;
            wv[p] = f2bf1(v0) | (f2bf1(v1) << 16);
        }
        W1f[idx] = make_uint4(wv[0],wv[1],wv[2],wv[3]);
    } else {
        int id2 = idx - 7*4*64;
        int lane = id2 & 63, kt = (id2>>6)&3, nt = id2>>8;
        int n = nt*16 + (lane&15);
        int kb = kt*32 + (lane>>4)*8;
        unsigned wv[4];
        #pragma unroll
        for (int p = 0; p < 4; ++p) {
            int k0 = kb+2*p, k1 = kb+2*p+1;
            float v0 = (k0 < H_) ? W2[k0*T_ + n] : 0.f;
            float v1 = (k1 < H_) ? W2[k1*T_ + n] : 0.f;
            wv[p] = f2bf1(v0) | (f2bf1(v1) << 16);
        }
        W2f[id2] = make_uint4(wv[0],wv[1],wv[2],wv[3]);
    }
}

// ---------------------------------------------------------------------------
// MLP (unchanged from round 10).
// ---------------------------------------------------------------------------
__global__ __launch_bounds__(256, 6) void mlp_kernel(
    const int* __restrict__ inputs, const unsigned short* __restrict__ tblh,
    const float* __restrict__ b1, const float* __restrict__ b2,
    const uint4* __restrict__ W1f, const uint4* __restrict__ W2f,
    unsigned short* __restrict__ em)
{
    __shared__ uint4 sA2[1024];

    const int tid  = threadIdx.x;
    const int lane = tid & 63;
    const int w    = tid >> 6;
    const int col  = lane & 15;
    const int hi   = lane >> 4;
    const int rowin = hi * 4;

    const int rg = blockIdx.x*64 + w*16 + col;
    const int i0 = inputs[rg*3+0], i1 = inputs[rg*3+1], i2 = inputs[rg*3+2];
    const unsigned short* tr0 = tblh + (size_t)i0*E_;
    const unsigned short* tr1 = tblh + (size_t)i1*E_;
    const unsigned short* tr2 = tblh + (size_t)i2*E_;

    U16x4 a[4];
    #pragma unroll
    for (int kt = 0; kt < 4; ++kt) {
        int off = kt*32 + hi*8;
        uint4 u0 = *(const uint4*)(tr0 + off);
        uint4 u1 = *(const uint4*)(tr1 + off);
        uint4 u2 = *(const uint4*)(tr2 + off);
        a[kt].u = make_uint4(addpack3(u0.x,u1.x,u2.x), addpack3(u0.y,u1.y,u2.y),
                             addpack3(u0.z,u1.z,u2.z), addpack3(u0.w,u1.w,u2.w));
    }

    f32x4 acc1[7];
    #pragma unroll
    for (int nt = 0; nt < 7; ++nt) {
        int n = nt*16 + col;
        float bv = (n < H_) ? b1[n] : 0.f;
        f32x4 c; c[0]=bv; c[1]=bv; c[2]=bv; c[3]=bv;
        #pragma unroll
        for (int k = 0; k < 4; ++k) {
            U16x4 bfr; bfr.u = W1f[(nt*4+k)*64 + lane];
            c = __builtin_amdgcn_mfma_f32_16x16x32_bf16(a[k].s, bfr.s, c, 0,0,0);
        }
        acc1[nt] = c;
    }
    #pragma unroll
    for (int nt = 0; nt < 7; ++nt)
        #pragma unroll
        for (int rr = 0; rr < 4; ++rr) {
            float x = acc1[nt][rr];
            acc1[nt][rr] = 1.f - 2.f/(__expf(2.f*x)+1.f);
        }

    if (lane >= 32) sA2[(w*4+3)*64 + lane] = make_uint4(0,0,0,0);
    unsigned short* A2h = (unsigned short*)sA2;
    #pragma unroll
    for (int nt = 0; nt < 7; ++nt)
        #pragma unroll
        for (int rr = 0; rr < 4; ++rr) {
            int k2 = nt*16 + col;
            int kt2 = k2 >> 5, g2 = (k2>>3)&3, i2v = k2&7;
            int u4idx = (w*4 + kt2)*64 + g2*16 + (rowin + rr);
            A2h[u4idx*8 + i2v] = (unsigned short)f2bf1(acc1[nt][rr]);
        }
    __builtin_amdgcn_wave_barrier();

    U16x4 a2[4];
    #pragma unroll
    for (int k = 0; k < 4; ++k) a2[k].u = sA2[(w*4+k)*64 + lane];
    __builtin_amdgcn_wave_barrier();

    unsigned short* tbuf = (unsigned short*)(sA2 + (size_t)w*256);
    #pragma unroll
    for (int nt2 = 0; nt2 < 4; ++nt2) {
        float bv = b2[nt2*16 + col];
        f32x4 c; c[0]=bv; c[1]=bv; c[2]=bv; c[3]=bv;
        #pragma unroll
        for (int k = 0; k < 4; ++k) {
            U16x4 bfr; bfr.u = W2f[(nt2*4+k)*64 + lane];
            c = __builtin_amdgcn_mfma_f32_16x16x32_bf16(a2[k].s, bfr.s, c, 0,0,0);
        }
        #pragma unroll
        for (int rr = 0; rr < 4; ++rr)
            tbuf[(rowin+rr)*72 + nt2*16 + col] = (unsigned short)f2bf1(c[rr]);
    }
    __builtin_amdgcn_wave_barrier();

    {
        const int rl = lane >> 2;
        const int ch = (lane & 3) * 2;
        const uint4* t4 = (const uint4*)tbuf;
        uint4 u0 = t4[rl*9 + ch];
        uint4 u1 = t4[rl*9 + ch + 1];
        size_t rowg = (size_t)(blockIdx.x*64 + w*16 + rl);
        uint4* dst = (uint4*)(em + rowg*T_);
        dst[ch]   = u0;
        dst[ch+1] = u1;
    }
}

// ---------------------------------------------------------------------------
// CRF scan via MFMA matvec. a held as 64 bf16 in LDS (128 B). Per step:
//   1 ds_write_b16 + 2 ds_read_b128 (A-frags, 16-lane broadcast) + 8 MFMA
//   (A rows all equal -> D rows all equal -> no reduction tree).
// Lane j owns col j: dot = acc[j>>4][0]; cand = dot*eg*sinv; select; write.
// E as B-frags (same k-map as prep_w, verified absmax=0 in mlp). 2 batches
// per wave for latency overlap. Rescale bookkeeping off-chain (r4 scheme).
// ---------------------------------------------------------------------------
__global__ __launch_bounds__(64)
__attribute__((amdgpu_waves_per_eu(1, 1)))
void crf_kernel(
    const int* __restrict__ inputs, const int* __restrict__ tags,
    const unsigned short* __restrict__ em, const float* __restrict__ start_trans,
    const float* __restrict__ end_trans, const float* __restrict__ trans,
    float* __restrict__ out)
{
    __shared__ __align__(16) unsigned short sem[2][512];   // em group staging
    __shared__ __align__(16) unsigned short alds[2][64];   // a as bf16

    const int j = threadIdx.x;
    const int col = j & 15;
    const int hi  = j >> 4;

    // E B-fragments: n = nt*16+col, k = kk*32 + hi*8 + i  (prep_w k-map)
    U16x4 Ebf[4][2];
    #pragma unroll
    for (int nt = 0; nt < 4; ++nt)
        #pragma unroll
        for (int kk = 0; kk < 2; ++kk) {
            int n = nt*16 + col;
            int kb = kk*32 + hi*8;
            unsigned wv[4];
            #pragma unroll
            for (int p = 0; p < 4; ++p) {
                float v0 = __expf(trans[(kb+2*p  )*T_ + n]);
                float v1 = __expf(trans[(kb+2*p+1)*T_ + n]);
                wv[p] = f2bf1(v0) | (f2bf1(v1) << 16);
            }
            Ebf[nt][kk].u = make_uint4(wv[0],wv[1],wv[2],wv[3]);
        }

    // per-chain state
    float av[2], ls[2], numer[2];
    unsigned long long mball[2][8];
    float eg[2][8];
    uint4 gbuf[2];
    const unsigned short* em_b[2];
    const float endj = end_trans[j];
    const float stj  = start_trans[j];

    #pragma unroll
    for (int c = 0; c < 2; ++c) {
        const int b = blockIdx.x*2 + c;
        em_b[c] = em + (size_t)b*S_*T_;
        const int* tags_b = tags + b*S_;
        const int* in_b = inputs + (size_t)b*S_*3;

        float partial = 0.f;
        #pragma unroll
        for (int g = 0; g < 8; ++g) {
            int t = g*64 + j;
            int a0 = in_b[t*3+0], a1 = in_b[t*3+1], a2 = in_b[t*3+2];
            bool mk = ((a0 | a1 | a2) != 0);
            mball[c][g] = __ballot(mk);
            if (t >= 1 && mk) {
                int tp = tags_b[t-1], tc = tags_b[t];
                partial += trans[tp*T_ + tc] + bf2f(em_b[c][(size_t)t*T_ + tc]);
            }
        }
        int mcount = 0;
        #pragma unroll
        for (int g = 0; g < 8; ++g) mcount += __popcll(mball[c][g]);
        mball[c][0] &= ~1ull;
        #pragma unroll
        for (int off = 32; off >= 1; off >>= 1) partial += __shfl_xor(partial, off, 64);
        const int tag0 = tags_b[0];
        int se = mcount - 1; if (se < 0) se = 0;
        const int last_tag = tags_b[se];
        numer[c] = partial + start_trans[tag0] + bf2f(em_b[c][tag0]) + end_trans[last_tag];

        float x0v = stj + bf2f(em_b[c][j]);
        ls[c] = rfl_f(x0v);
        av[c] = __expf(x0v - ls[c]);
        alds[c][j] = (unsigned short)f2bf1(av[c]);
        gbuf[c] = ((const uint4*)em_b[c])[j];           // group 0
    }

    for (int g = 0; g < 64; ++g) {
        #pragma unroll
        for (int c = 0; c < 2; ++c) ((uint4*)sem[c])[j] = gbuf[c];
        __builtin_amdgcn_wave_barrier();
        if (g < 63) {
            #pragma unroll
            for (int c = 0; c < 2; ++c)
                gbuf[c] = ((const uint4*)em_b[c])[(g+1)*64 + j];
        }
        #pragma unroll
        for (int c = 0; c < 2; ++c)
            #pragma unroll
            for (int k = 0; k < 8; ++k)
                eg[c][k] = __expf(bf2f(sem[c][k*T_ + j]));
        unsigned mg[2];
        #pragma unroll
        for (int c = 0; c < 2; ++c)
            mg[c] = (unsigned)((mball[c][g>>3] >> ((g&7)*8)) & 0xFFull);

        #pragma unroll
        for (int s = 0; s < 8; ++s) {
            // off-chain scale prep from current av
            float sc[2], sinv[2], logs[2], keep[2], dmul[2];
            #pragma unroll
            for (int c = 0; c < 2; ++c) {
                sc[c]   = rfl_f(av[c]);
                sinv[c] = __builtin_amdgcn_rcpf(sc[c]);
                logs[c] = __logf(sc[c]);
                keep[c] = av[c] * sinv[c];
                dmul[c] = eg[c][s] * sinv[c];
            }
            // A-frags from LDS: addr depends only on hi -> rows all equal
            U16x4 af[2][2];
            #pragma unroll
            for (int c = 0; c < 2; ++c) {
                const uint4* a4 = (const uint4*)alds[c];
                af[c][0].u = a4[hi];
                af[c][1].u = a4[4 + hi];
            }
            #pragma unroll
            for (int c = 0; c < 2; ++c) {
                f32x4 acc[4];
                #pragma unroll
                for (int nt = 0; nt < 4; ++nt) {
                    f32x4 z; z[0]=0.f; z[1]=0.f; z[2]=0.f; z[3]=0.f;
                    z = __builtin_amdgcn_mfma_f32_16x16x32_bf16(af[c][0].s, Ebf[nt][0].s, z, 0,0,0);
                    z = __builtin_amdgcn_mfma_f32_16x16x32_bf16(af[c][1].s, Ebf[nt][1].s, z, 0,0,0);
                    acc[nt] = z;
                }
                // lane j's column j dot: acc[j>>4][0] (all rows equal)
                float d01 = (hi & 1) ? acc[1][0] : acc[0][0];
                float d23 = (hi & 1) ? acc[3][0] : acc[2][0];
                float dot = (hi & 2) ? d23 : d01;
                float cand = dot * dmul[c];
                av[c] = ((mg[c] >> s) & 1u) ? cand : keep[c];
                ls[c] += logs[c];
            }
            __builtin_amdgcn_wave_barrier();
            #pragma unroll
            for (int c = 0; c < 2; ++c)
                alds[c][j] = (unsigned short)f2bf1(av[c]);
            __builtin_amdgcn_wave_barrier();
        }
    }

    #pragma unroll
    for (int c = 0; c < 2; ++c) {
        float x = av[c] * __expf(endj);
        #pragma unroll
        for (int off = 32; off >= 1; off >>= 1) x += __shfl_xor(x, off, 64);
        if (j == 0) out[blockIdx.x*2 + c] = ls[c] + __logf(x) - numer[c];
    }
}

// ---------------------------------------------------------------------------
extern "C" void kernel_launch(void* const* d_in, const int* in_sizes, int n_in,
                              void* d_out, int out_size, void* d_ws, size_t ws_size,
                              hipStream_t stream) {
    const int*   inputs      = (const int*)  d_in[0];
    const int*   tags        = (const int*)  d_in[1];
    const float* emb_table   = (const float*)d_in[2];
    const float* W1          = (const float*)d_in[3];
    const float* b1          = (const float*)d_in[4];
    const float* W2          = (const float*)d_in[5];
    const float* b2          = (const float*)d_in[6];
    const float* start_trans = (const float*)d_in[7];
    const float* end_trans   = (const float*)d_in[8];
    const float* transitions = (const float*)d_in[9];
    float* out = (float*)d_out;

    // ws: em bf16 (32 MiB) | W1f 28KB | W2f 16KB | tblh bf16 (25.6 MB)
    unsigned short* em = (unsigned short*)d_ws;
    uint4* W1f = (uint4*)((char*)d_ws + (size_t)BS_*T_*2);
    uint4* W2f = W1f + 7*4*64;
    unsigned short* tblh = (unsigned short*)((char*)d_ws + (size_t)BS_*T_*2 + 28672 + 16384);

    prep_tbl<<<dim3((V_*E_/4 + 255)/256), dim3(256), 0, stream>>>(emb_table, (uint2*)tblh);
    prep_w<<<dim3((7*4*64 + 4*4*64)/64), dim3(64), 0, stream>>>(W1, W2, W1f, W2f);
    mlp_kernel<<<dim3(BS_/64), dim3(256), 0, stream>>>(
        inputs, tblh, b1, b2, W1f, W2f, em);
    crf_kernel<<<dim3(B_/2), dim3(64), 0, stream>>>(
        inputs, tags, em, start_trans, end_trans, transitions, out);
}

// Round 12
// 321.431 us; speedup vs baseline: 1.2461x; 1.2461x over previous
//
#include <hip/hip_runtime.h>

#define B_ 512
#define S_ 512
#define E_ 128
#define H_ 100
#define T_ 64
#define V_ 100000
#define BS_ (B_*S_)

typedef __attribute__((ext_vector_type(8))) short bf16x8;
typedef __attribute__((ext_vector_type(4))) float f32x4;
typedef __attribute__((ext_vector_type(2))) float f32x2;
union U16x4 { uint4 u; bf16x8 s; };

__device__ __forceinline__ unsigned f2bf1(float x){
    unsigned u = __float_as_uint(x);
    return (u + 0x7FFFu + ((u>>16)&1u)) >> 16;
}
__device__ __forceinline__ float bf2f(unsigned short h){
    return __uint_as_float(((unsigned)h)<<16);
}
__device__ __forceinline__ float rfl_f(float x){
    return __uint_as_float(__builtin_amdgcn_readfirstlane(__float_as_uint(x)));
}
__device__ __forceinline__ unsigned addpack3(unsigned a, unsigned b, unsigned c){
    float lo = __uint_as_float(a<<16) + __uint_as_float(b<<16) + __uint_as_float(c<<16);
    float hi = __uint_as_float(a&0xFFFF0000u) + __uint_as_float(b&0xFFFF0000u)
             + __uint_as_float(c&0xFFFF0000u);
    return f2bf1(lo) | (f2bf1(hi)<<16);
}

// ---------------------------------------------------------------------------
// prep_tbl: fp32 emb table -> bf16 copy.
// ---------------------------------------------------------------------------
__global__ __launch_bounds__(256) void prep_tbl(
    const float* __restrict__ tbl, uint2* __restrict__ tblh)
{
    int idx = blockIdx.x*256 + threadIdx.x;
    if (idx < (V_*E_)/4) {
        float4 v = ((const float4*)tbl)[idx];
        uint2 o;
        o.x = f2bf1(v.x) | (f2bf1(v.y)<<16);
        o.y = f2bf1(v.z) | (f2bf1(v.w)<<16);
        tblh[idx] = o;
    }
}

// ---------------------------------------------------------------------------
// prep_w: W1/W2 bf16 MFMA B-fragment images.
// ---------------------------------------------------------------------------
__global__ __launch_bounds__(64) void prep_w(
    const float* __restrict__ W1, const float* __restrict__ W2,
    uint4* __restrict__ W1f, uint4* __restrict__ W2f)
{
    const int idx = blockIdx.x*64 + threadIdx.x;
    if (idx < 7*4*64) {
        int lane = idx & 63, kt = (idx>>6)&3, nt = idx>>8;
        int n = nt*16 + (lane&15);
        int kb = kt*32 + (lane>>4)*8;
        unsigned wv[4];
        #pragma unroll
        for (int p = 0; p < 4; ++p) {
            float v0 = (n < H_) ? W1[(kb+2*p  )*H_ + n] : 0.f;
            float v1 = (n < H_) ? W1[(kb+2*p+1)*H_ + n] : 0.f;
            wv[p] = f2bf1(v0) | (f2bf1(v1) << 16);
        }
        W1f[idx] = make_uint4(wv[0],wv[1],wv[2],wv[3]);
    } else {
        int id2 = idx - 7*4*64;
        int lane = id2 & 63, kt = (id2>>6)&3, nt = id2>>8;
        int n = nt*16 + (lane&15);
        int kb = kt*32 + (lane>>4)*8;
        unsigned wv[4];
        #pragma unroll
        for (int p = 0; p < 4; ++p) {
            int k0 = kb+2*p, k1 = kb+2*p+1;
            float v0 = (k0 < H_) ? W2[k0*T_ + n] : 0.f;
            float v1 = (k1 < H_) ? W2[k1*T_ + n] : 0.f;
            wv[p] = f2bf1(v0) | (f2bf1(v1) << 16);
        }
        W2f[id2] = make_uint4(wv[0],wv[1],wv[2],wv[3]);
    }
}

// ---------------------------------------------------------------------------
// MLP (unchanged — control).
// ---------------------------------------------------------------------------
__global__ __launch_bounds__(256, 6) void mlp_kernel(
    const int* __restrict__ inputs, const unsigned short* __restrict__ tblh,
    const float* __restrict__ b1, const float* __restrict__ b2,
    const uint4* __restrict__ W1f, const uint4* __restrict__ W2f,
    unsigned short* __restrict__ em)
{
    __shared__ uint4 sA2[1024];

    const int tid  = threadIdx.x;
    const int lane = tid & 63;
    const int w    = tid >> 6;
    const int col  = lane & 15;
    const int hi   = lane >> 4;
    const int rowin = hi * 4;

    const int rg = blockIdx.x*64 + w*16 + col;
    const int i0 = inputs[rg*3+0], i1 = inputs[rg*3+1], i2 = inputs[rg*3+2];
    const unsigned short* tr0 = tblh + (size_t)i0*E_;
    const unsigned short* tr1 = tblh + (size_t)i1*E_;
    const unsigned short* tr2 = tblh + (size_t)i2*E_;

    U16x4 a[4];
    #pragma unroll
    for (int kt = 0; kt < 4; ++kt) {
        int off = kt*32 + hi*8;
        uint4 u0 = *(const uint4*)(tr0 + off);
        uint4 u1 = *(const uint4*)(tr1 + off);
        uint4 u2 = *(const uint4*)(tr2 + off);
        a[kt].u = make_uint4(addpack3(u0.x,u1.x,u2.x), addpack3(u0.y,u1.y,u2.y),
                             addpack3(u0.z,u1.z,u2.z), addpack3(u0.w,u1.w,u2.w));
    }

    f32x4 acc1[7];
    #pragma unroll
    for (int nt = 0; nt < 7; ++nt) {
        int n = nt*16 + col;
        float bv = (n < H_) ? b1[n] : 0.f;
        f32x4 c; c[0]=bv; c[1]=bv; c[2]=bv; c[3]=bv;
        #pragma unroll
        for (int k = 0; k < 4; ++k) {
            U16x4 bfr; bfr.u = W1f[(nt*4+k)*64 + lane];
            c = __builtin_amdgcn_mfma_f32_16x16x32_bf16(a[k].s, bfr.s, c, 0,0,0);
        }
        acc1[nt] = c;
    }
    #pragma unroll
    for (int nt = 0; nt < 7; ++nt)
        #pragma unroll
        for (int rr = 0; rr < 4; ++rr) {
            float x = acc1[nt][rr];
            acc1[nt][rr] = 1.f - 2.f/(__expf(2.f*x)+1.f);
        }

    if (lane >= 32) sA2[(w*4+3)*64 + lane] = make_uint4(0,0,0,0);
    unsigned short* A2h = (unsigned short*)sA2;
    #pragma unroll
    for (int nt = 0; nt < 7; ++nt)
        #pragma unroll
        for (int rr = 0; rr < 4; ++rr) {
            int k2 = nt*16 + col;
            int kt2 = k2 >> 5, g2 = (k2>>3)&3, i2v = k2&7;
            int u4idx = (w*4 + kt2)*64 + g2*16 + (rowin + rr);
            A2h[u4idx*8 + i2v] = (unsigned short)f2bf1(acc1[nt][rr]);
        }
    __builtin_amdgcn_wave_barrier();

    U16x4 a2[4];
    #pragma unroll
    for (int k = 0; k < 4; ++k) a2[k].u = sA2[(w*4+k)*64 + lane];
    __builtin_amdgcn_wave_barrier();

    unsigned short* tbuf = (unsigned short*)(sA2 + (size_t)w*256);
    #pragma unroll
    for (int nt2 = 0; nt2 < 4; ++nt2) {
        float bv = b2[nt2*16 + col];
        f32x4 c; c[0]=bv; c[1]=bv; c[2]=bv; c[3]=bv;
        #pragma unroll
        for (int k = 0; k < 4; ++k) {
            U16x4 bfr; bfr.u = W2f[(nt2*4+k)*64 + lane];
            c = __builtin_amdgcn_mfma_f32_16x16x32_bf16(a2[k].s, bfr.s, c, 0,0,0);
        }
        #pragma unroll
        for (int rr = 0; rr < 4; ++rr)
            tbuf[(rowin+rr)*72 + nt2*16 + col] = (unsigned short)f2bf1(c[rr]);
    }
    __builtin_amdgcn_wave_barrier();

    {
        const int rl = lane >> 2;
        const int ch = (lane & 3) * 2;
        const uint4* t4 = (const uint4*)tbuf;
        uint4 u0 = t4[rl*9 + ch];
        uint4 u1 = t4[rl*9 + ch + 1];
        size_t rowg = (size_t)(blockIdx.x*64 + w*16 + rl);
        uint4* dst = (uint4*)(em + rowg*T_);
        dst[ch]   = u0;
        dst[ch+1] = u1;
    }
}

// ---------------------------------------------------------------------------
// CRF BIDIRECTIONAL scan: sequential depth halved (512 -> 256 iterations).
//   Z = e_end^T M_511...M_1 a0 ;  M_t(a) = mask_t ? diag(e_t) E^T a : a
// fwd:  a <- mask ? (E^T a) o e_t : a      (t = 1..255; bit0 cleared)
// bwd:  b <- mask ? E (e_t o b) : b        (t = 511 down to 256)
// merge: logZ = lsF + lsB + log(sum_j aF_j * aB_j).
// Both chains in one wave; per-step broadcast via LDS (r4 primitive, 768cyc),
// B-chain reads/tree overlap F-chain latency. em rows: fwd groups 0..31,
// bwd groups 63..32 — each row read exactly once.
// ---------------------------------------------------------------------------
__global__ __launch_bounds__(64)
__attribute__((amdgpu_waves_per_eu(1, 1)))
void crf_kernel(
    const int* __restrict__ inputs, const int* __restrict__ tags,
    const unsigned short* __restrict__ em, const float* __restrict__ start_trans,
    const float* __restrict__ end_trans, const float* __restrict__ trans,
    float* __restrict__ out)
{
    __shared__ __align__(16) unsigned short semF[2][512];
    __shared__ __align__(16) unsigned short semB[2][512];
    __shared__ __align__(16) float pbufF[T_];
    __shared__ __align__(16) float pbufB[T_];

    const int b = blockIdx.x;
    const int j = threadIdx.x;
    const unsigned short* em_b = em + (size_t)b*S_*T_;
    const int* tags_b = tags + b*S_;
    const int* in_b = inputs + (size_t)b*S_*3;

    // mask ballots + numerator (r4 verbatim)
    unsigned long long mball[8];
    float partial = 0.f;
    #pragma unroll
    for (int g = 0; g < 8; ++g) {
        int t = g*64 + j;
        int a0 = in_b[t*3+0], a1 = in_b[t*3+1], a2 = in_b[t*3+2];
        bool mk = ((a0 | a1 | a2) != 0);
        mball[g] = __ballot(mk);
        if (t >= 1 && mk) {
            int tp = tags_b[t-1], tc = tags_b[t];
            partial += trans[tp*T_ + tc] + bf2f(em_b[(size_t)t*T_ + tc]);
        }
    }
    int mcount = 0;
    #pragma unroll
    for (int g = 0; g < 8; ++g) mcount += __popcll(mball[g]);
    mball[0] &= ~1ull;
    #pragma unroll
    for (int off = 32; off >= 1; off >>= 1) partial += __shfl_xor(partial, off, 64);
    const int tag0 = tags_b[0];
    int se = mcount - 1; if (se < 0) se = 0;
    const int last_tag = tags_b[se];
    const float numer = partial + start_trans[tag0] + bf2f(em_b[tag0]) + end_trans[last_tag];

    // E2F[i] = E column j pairs (fwd);  E2B[i] = E row j pairs (bwd)
    f32x2 E2F[32], E2B[32];
    #pragma unroll
    for (int i = 0; i < 32; ++i) {
        f32x2 ef; ef.x = __expf(trans[(2*i)*T_ + j]);  ef.y = __expf(trans[(2*i+1)*T_ + j]);
        E2F[i] = ef;
        f32x2 eb; eb.x = __expf(trans[j*T_ + 2*i]);    eb.y = __expf(trans[j*T_ + 2*i+1]);
        E2B[i] = eb;
    }

    // init: fwd a = exp(start+em0 - lsF); bwd b = exp(end), lsB = 0
    float x0v = start_trans[j] + bf2f(em_b[j]);
    float lsF = rfl_f(x0v);
    float aF = __expf(x0v - lsF);
    float aB = __expf(end_trans[j]);
    float lsB = 0.f;

    // staging prologue: fwd group 0, bwd group 63
    const uint4* em4 = (const uint4*)em_b;
    uint4 gF = em4[j];
    uint4 gB = em4[63*64 + j];
    ((uint4*)semF[0])[j] = gF;
    ((uint4*)semB[0])[j] = gB;
    __builtin_amdgcn_wave_barrier();
    float egF[8], egB[8];
    #pragma unroll
    for (int s = 0; s < 8; ++s) egF[s] = __expf(bf2f(semF[0][s*T_ + j]));
    #pragma unroll
    for (int s = 0; s < 8; ++s) egB[s] = __expf(bf2f(semB[0][(7-s)*T_ + j]));
    gF = em4[64 + j];
    gB = em4[62*64 + j];

    auto matv = [&](const float4* p4, const f32x2* E2) -> float {
        f32x2 ac0={0.f,0.f}, ac1={0.f,0.f}, ac2={0.f,0.f}, ac3={0.f,0.f};
        #pragma unroll
        for (int q = 0; q < 4; ++q) {
            float4 A0 = p4[4*q+0], A1 = p4[4*q+1], A2v = p4[4*q+2], A3 = p4[4*q+3];
            f32x2 p0; p0.x=A0.x; p0.y=A0.y;  f32x2 p1; p1.x=A0.z; p1.y=A0.w;
            f32x2 p2; p2.x=A1.x; p2.y=A1.y;  f32x2 p3; p3.x=A1.z; p3.y=A1.w;
            f32x2 p4v; p4v.x=A2v.x;p4v.y=A2v.y; f32x2 p5; p5.x=A2v.z;p5.y=A2v.w;
            f32x2 p6; p6.x=A3.x; p6.y=A3.y;  f32x2 p7; p7.x=A3.z; p7.y=A3.w;
            ac0 = p0 *E2[8*q+0] + ac0;  ac1 = p1*E2[8*q+1] + ac1;
            ac2 = p2 *E2[8*q+2] + ac2;  ac3 = p3*E2[8*q+3] + ac3;
            ac0 = p4v*E2[8*q+4] + ac0;  ac1 = p5*E2[8*q+5] + ac1;
            ac2 = p6 *E2[8*q+6] + ac2;  ac3 = p7*E2[8*q+7] + ac3;
        }
        f32x2 st = (ac0+ac1)+(ac2+ac3);
        return st.x + st.y;
    };

    for (int k = 0; k < 32; ++k) {
        unsigned short rawF[8], rawB[8];
        if (k < 31) {
            ((uint4*)semF[(k+1)&1])[j] = gF;
            ((uint4*)semB[(k+1)&1])[j] = gB;
            __builtin_amdgcn_wave_barrier();
            #pragma unroll
            for (int s = 0; s < 8; ++s) rawF[s] = semF[(k+1)&1][s*T_ + j];
            #pragma unroll
            for (int s = 0; s < 8; ++s) rawB[s] = semB[(k+1)&1][(7-s)*T_ + j];
            if (k < 30) {
                gF = em4[(k+2)*64 + j];
                gB = em4[(61-k)*64 + j];
            }
        }
        const unsigned mgF = (unsigned)((mball[k>>3] >> ((k&7)*8)) & 0xFFull);
        const int kb = 63 - k;
        const unsigned mgB = (unsigned)((mball[kb>>3] >> ((kb&7)*8)) & 0xFFull);

        #pragma unroll
        for (int s = 0; s < 8; ++s) {
            pbufF[j] = aF;                      // fwd broadcasts unscaled a
            float pbB = egB[s] * aB;            // bwd: e_t o b BEFORE matvec
            pbufB[j] = pbB;
            __builtin_amdgcn_wave_barrier();
            // off-chain scale prep (overlaps LDS round-trip)
            float sF    = rfl_f(aF);
            float sB    = rfl_f(aB);
            float sinvF = __builtin_amdgcn_rcpf(sF);
            float sinvB = __builtin_amdgcn_rcpf(sB);
            float logsF = __logf(sF);
            float logsB = __logf(sB);
            float keepF = aF * sinvF;
            float keepB = aB * sinvB;
            float dmulF = egF[s] * sinvF;

            float dotF = matv((const float4*)pbufF, E2F);
            float dotB = matv((const float4*)pbufB, E2B);

            float candF = dotF * dmulF;
            float candB = dotB * sinvB;
            aF = ((mgF >> s)     & 1u) ? candF : keepF;
            aB = ((mgB >> (7-s)) & 1u) ? candB : keepB;
            lsF += logsF;
            lsB += logsB;
            __builtin_amdgcn_wave_barrier();
        }
        if (k < 31) {
            #pragma unroll
            for (int s = 0; s < 8; ++s) egF[s] = __expf(bf2f(rawF[s]));
            #pragma unroll
            for (int s = 0; s < 8; ++s) egB[s] = __expf(bf2f(rawB[s]));
        }
    }

    // merge: logZ = lsF + lsB + log(sum_j aF_j * aB_j)
    float x = aF * aB;
    #pragma unroll
    for (int off = 32; off >= 1; off >>= 1) x += __shfl_xor(x, off, 64);
    if (j == 0) out[b] = lsF + lsB + __logf(x) - numer;
}

// ---------------------------------------------------------------------------
extern "C" void kernel_launch(void* const* d_in, const int* in_sizes, int n_in,
                              void* d_out, int out_size, void* d_ws, size_t ws_size,
                              hipStream_t stream) {
    const int*   inputs      = (const int*)  d_in[0];
    const int*   tags        = (const int*)  d_in[1];
    const float* emb_table   = (const float*)d_in[2];
    const float* W1          = (const float*)d_in[3];
    const float* b1          = (const float*)d_in[4];
    const float* W2          = (const float*)d_in[5];
    const float* b2          = (const float*)d_in[6];
    const float* start_trans = (const float*)d_in[7];
    const float* end_trans   = (const float*)d_in[8];
    const float* transitions = (const float*)d_in[9];
    float* out = (float*)d_out;

    // ws: em bf16 (32 MiB) | W1f 28KB | W2f 16KB | tblh bf16 (25.6 MB)
    unsigned short* em = (unsigned short*)d_ws;
    uint4* W1f = (uint4*)((char*)d_ws + (size_t)BS_*T_*2);
    uint4* W2f = W1f + 7*4*64;
    unsigned short* tblh = (unsigned short*)((char*)d_ws + (size_t)BS_*T_*2 + 28672 + 16384);

    prep_tbl<<<dim3((V_*E_/4 + 255)/256), dim3(256), 0, stream>>>(emb_table, (uint2*)tblh);
    prep_w<<<dim3((7*4*64 + 4*4*64)/64), dim3(64), 0, stream>>>(W1, W2, W1f, W2f);
    mlp_kernel<<<dim3(BS_/64), dim3(256), 0, stream>>>(
        inputs, tblh, b1, b2, W1f, W2f, em);
    crf_kernel<<<dim3(B_), dim3(64), 0, stream>>>(
        inputs, tags, em, start_trans, end_trans, transitions, out);
}